// Round 9
// baseline (273.434 us; speedup 1.0000x reference)
//
#include <hip/hip_runtime.h>
#include <math.h>

#define SEQ 2048
#define DMODEL 1024
#define NH 16
#define HD 64
#define BH 64                      // B*NH
#define MROWS 8192                 // B*SEQ
#define QKV_U16 8388608            // BH*SEQ*HD elements (== MROWS*DMODEL)
#define LOG2E 1.4426950408889634f

typedef __attribute__((ext_vector_type(8))) _Float16 half8;
typedef __attribute__((ext_vector_type(4))) _Float16 half4;
typedef __attribute__((ext_vector_type(2))) __fp16 fp16v2;
typedef __attribute__((ext_vector_type(8))) short short8;
typedef __attribute__((ext_vector_type(4))) float floatx4;
typedef unsigned short ush;

union FH { _Float16 h; ush u; };
union PK { fp16v2 v; unsigned u; };
union PH { unsigned u[2]; half4 h; };

__device__ inline ush f2h(float x) { FH c; c.h = (_Float16)x; return c.u; }

// global -> LDS direct DMA, 16B per lane. LDS dest must be wave-uniform;
// HW writes lane i at ldsbase + i*16 (m104/m108). Global addr is per-lane.
__device__ inline void glds16(const ush* g, ush* l) {
  __builtin_amdgcn_global_load_lds((const __attribute__((address_space(1))) void*)g,
                                   (__attribute__((address_space(3))) void*)l, 16, 0, 0);
}

// ---------------------------------------------------------------------------
// Convert fp32 [M][1024] -> fp16 k-block-major: dst[(k/8)][M][8].
// ---------------------------------------------------------------------------
__global__ __launch_bounds__(256)
void cvt_kb(const float* __restrict__ src, ush* __restrict__ dst, int M) {
  __shared__ float T[64][33];
  const int t = threadIdx.x;
  const int k0 = blockIdx.x * 32, m0 = blockIdx.y * 64;
  {
    int row = t >> 2, c = (t & 3) * 8;
    const float* sp = src + (size_t)(m0 + row) * DMODEL + k0 + c;
    float4 x0 = *(const float4*)sp;
    float4 x1 = *(const float4*)(sp + 4);
    float xs[8] = {x0.x, x0.y, x0.z, x0.w, x1.x, x1.y, x1.z, x1.w};
#pragma unroll
    for (int j = 0; j < 8; ++j) T[row][c + j] = xs[j];
  }
  __syncthreads();
  const int ml = t & 63, kbl = t >> 6;
  short8 h8;
#pragma unroll
  for (int j = 0; j < 8; ++j) h8[j] = (short)f2h(T[ml][kbl * 8 + j]);
  *(short8*)(dst + ((size_t)(k0 / 8 + kbl) * M + m0 + ml) * 8) = h8;
}

// 4 weight matrices in one launch (blockIdx.z selects); z==3 plane also
// fills the RoPE sin/cos table (512 blocks cover the 65536 entries).
__global__ __launch_bounds__(256)
void cvt_w4(const float* __restrict__ W0, const float* __restrict__ W1,
            const float* __restrict__ W2, const float* __restrict__ W3,
            ush* __restrict__ dst, float2* __restrict__ tab) {
  __shared__ float T[64][33];
  const int z = blockIdx.z;
  if (z == 3) {
    const int idx = (blockIdx.y * 32 + blockIdx.x) * 256 + threadIdx.x;
    if (idx < 65536) {
      const int s = idx >> 5, i = idx & 31;
      const float f = (float)pow(10000.0, -(double)i / 32.0);
      const float ang = (float)s * f;
      tab[idx] = make_float2(sinf(ang), cosf(ang));
    }
  }
  const float* src = (z == 0) ? W0 : (z == 1) ? W1 : (z == 2) ? W2 : W3;
  ush* dz = dst + (size_t)z * DMODEL * DMODEL;
  const int t = threadIdx.x;
  const int k0 = blockIdx.x * 32, m0 = blockIdx.y * 64;
  {
    int row = t >> 2, c = (t & 3) * 8;
    const float* sp = src + (size_t)(m0 + row) * DMODEL + k0 + c;
    float4 x0 = *(const float4*)sp;
    float4 x1 = *(const float4*)(sp + 4);
    float xs[8] = {x0.x, x0.y, x0.z, x0.w, x1.x, x1.y, x1.z, x1.w};
#pragma unroll
    for (int j = 0; j < 8; ++j) T[row][c + j] = xs[j];
  }
  __syncthreads();
  const int ml = t & 63, kbl = t >> 6;
  short8 h8;
#pragma unroll
  for (int j = 0; j < 8; ++j) h8[j] = (short)f2h(T[ml][kbl * 8 + j]);
  *(short8*)(dz + ((size_t)(k0 / 8 + kbl) * DMODEL + m0 + ml) * 8) = h8;
}

// ---------------------------------------------------------------------------
// fp16 MFMA GEMM (NT), LDS-staged with T4 counted-vmcnt pipeline.
// R8 lesson: the T4 loop at BM=128 ran only 16 MFMAs between barriers —
// barrier-amortization-bound (~670 TF). This round: BM=256 doubles the
// per-barrier MFMA count (32/wave) at +50% staging; acc 8x4 (~200 VGPR,
// fits 2 waves/SIMD).
//   - 3 LDS buffers (72 KB total -> 2 blocks/CU); stage(t+2) at iter t.
//   - per-wave counted s_waitcnt vmcnt(6) (6 own glds16 per tile) + raw
//     s_barrier; loads for t+2 stay in flight ACROSS the barrier; vmcnt(0)
//     only at the tail. (R6-R8: verified correct.)
//   - T5 s_setprio(1) around the MFMA cluster (counted-vmcnt loop has
//     wave role diversity = the m218b-positive regime).
// Geometry: BM=256, BN=128, BK=32; 4 waves, wave = 128m x 64n (acc 8x4).
// QKV==1: Q,K,V fused, grid (24,32) = 768 blocks (blockIdx.x>>3 selects
//   panel). QKV==0: out-proj, grid (8,32) = 256 blocks.
// Staging: wave-uniform LDS base + lane*16 (m104); contiguous 1KB/wave.
// RoPE via precomputed sin/cos table (reference has sin/cos names swapped:
// new1 = x1*sin - x2*cos ; new2 = x2*sin + x1*cos).
// ---------------------------------------------------------------------------
template<int QKV>
__global__ __launch_bounds__(256, 2)
void gemm_f16(const ush* __restrict__ A, const ush* __restrict__ W0,
              const float* __restrict__ b0, const float* __restrict__ b1,
              const float* __restrict__ b2, void* __restrict__ out0,
              void* __restrict__ out1, void* __restrict__ out2,
              const float2* __restrict__ sctab) {
  constexpr int NT = 32;                   // K / BK(=32) tiles
  __shared__ ush SA[3][8192];              // 4 kb x 256 rows x 8 = 16 KB each
  __shared__ ush SW[3][4096];              // 4 kb x 128 rows x 8 = 8 KB each
  const int tid  = threadIdx.x;
  const int wave = tid >> 6;
  const int lane = tid & 63;
  const int fr = lane & 15;
  const int fg = lane >> 4;
  const int wm = wave & 1;
  const int wn = wave >> 1;

  const int zz = QKV ? (blockIdx.x >> 3) : 3;         // 0=Q 1=K 2=V 3=out
  const int nx = QKV ? (blockIdx.x & 7) : blockIdx.x;
  const int m0 = blockIdx.y * 256;
  const int n0 = nx * 128;
  const int m_base = m0 + wm * 128;
  const int n_base = n0 + wn * 64;

  const ush* W = W0 + (size_t)(QKV ? zz : 0) * (DMODEL * DMODEL);
  const float* bias = QKV ? (zz == 0 ? b0 : zz == 1 ? b1 : b2) : b0;
  void* outp = QKV ? (zz == 0 ? out0 : zz == 1 ? out1 : out2) : out0;
  const float scale = (QKV && zz == 0) ? 0.125f * LOG2E : 1.0f;

  floatx4 acc[8][4];
#pragma unroll
  for (int i = 0; i < 8; ++i)
#pragma unroll
    for (int j = 0; j < 4; ++j) acc[i][j] = (floatx4){0.f, 0.f, 0.f, 0.f};

  // stage one BK=32 tile into buffer b: 6 glds16 per wave (A 4 + W 2)
  auto stage = [&](int b, int kt) {
    const int kb0 = kt * 4;
#pragma unroll
    for (int p = 0; p < 4; ++p) {
      const int c = p * 256 + wave * 64;            // kb = p, rows wave*64..
      glds16(A + (size_t)(kb0 + p) * (MROWS * 8) + (size_t)(m0 + (c & 255) + lane) * 8,
             &SA[b][(size_t)c * 8]);
    }
#pragma unroll
    for (int p = 0; p < 2; ++p) {
      const int c = p * 256 + wave * 64;
      const int kb = c >> 7, r0 = c & 127;
      glds16(W + (size_t)(kb0 + kb) * (DMODEL * 8) + (size_t)(n0 + r0 + lane) * 8,
             &SW[b][(size_t)c * 8]);
    }
  };

  auto compute = [&](int b) {
    const int kbl = fg;                          // 4 k-blocks = BK 32
    half8 ah[8], wh[4];
#pragma unroll
    for (int tm = 0; tm < 8; ++tm)
      ah[tm] = *(const half8*)&SA[b][(size_t)(kbl * 256 + wm * 128 + tm * 16 + fr) * 8];
#pragma unroll
    for (int tn = 0; tn < 4; ++tn)
      wh[tn] = *(const half8*)&SW[b][(size_t)(kbl * 128 + wn * 64 + tn * 16 + fr) * 8];
    __builtin_amdgcn_s_setprio(1);
#pragma unroll
    for (int tm = 0; tm < 8; ++tm)
#pragma unroll
      for (int tn = 0; tn < 4; ++tn)
        acc[tm][tn] = __builtin_amdgcn_mfma_f32_16x16x32_f16(ah[tm], wh[tn], acc[tm][tn], 0, 0, 0);
    __builtin_amdgcn_s_setprio(0);
  };

  // ---- prologue: 2 tiles in flight, wait only the oldest
  stage(0, 0);
  stage(1, 1);
  asm volatile("s_waitcnt vmcnt(6)" ::: "memory");
  __builtin_amdgcn_s_barrier();
  __builtin_amdgcn_sched_barrier(0);

  int bc = 0;
  for (int t = 0; t < NT; ++t) {
    if (t + 2 < NT) {
      int bs = bc + 2; if (bs >= 3) bs -= 3;
      stage(bs, t + 2);
    }
    compute(bc);
    if (t + 1 < NT) {
      if (t + 2 < NT) {
        asm volatile("s_waitcnt vmcnt(6)" ::: "memory");
      } else {
        asm volatile("s_waitcnt vmcnt(0)" ::: "memory");
      }
      __builtin_amdgcn_s_barrier();
      __builtin_amdgcn_sched_barrier(0);
    }
    ++bc; if (bc == 3) bc = 0;
  }

  float bias_s[4];
#pragma unroll
  for (int tn = 0; tn < 4; ++tn) bias_s[tn] = bias[n_base + tn * 16 + fr];

  if (!QKV) {                           // out-proj: fp32 row-major
#pragma unroll
    for (int tm = 0; tm < 8; ++tm)
#pragma unroll
      for (int tn = 0; tn < 4; ++tn)
#pragma unroll
        for (int r = 0; r < 4; ++r) {
          const int m = m_base + tm * 16 + fg * 4 + r;
          const int n = n_base + tn * 16 + fr;
          ((float*)outp)[(size_t)m * DMODEL + n] = acc[tm][tn][r] + bias_s[tn];
        }
    return;
  }

  const int h = (n_base >> 6) & 15;
  ush* out = (ush*)outp;

  if (zz == 2) {                        // V: no rope, K-frag layout for PV
#pragma unroll
    for (int tm = 0; tm < 8; ++tm)
#pragma unroll
      for (int tn = 0; tn < 4; ++tn)
#pragma unroll
        for (int r = 0; r < 4; ++r) {
          const int m = m_base + tm * 16 + fg * 4 + r;
          const int s = m & (SEQ - 1);
          const size_t bh = (size_t)((m >> 11) * NH + h);
          const int d = tn * 16 + fr;
          const int k6 = s & 63, ktl = s >> 6;
          const int s2 = k6 >> 5;
          const int jj = ((k6 >> 4) & 1) * 4 + (k6 & 3);
          const int fgv = (k6 >> 2) & 3;
          const int dt = d >> 4, frv = d & 15;
          size_t pos = ((((bh * 32 + ktl) * 4 + dt) * 2 + s2) * 64 + fgv * 16 + frv) * 8 + jj;
          out[pos] = f2h(acc[tm][tn][r] + bias_s[tn]);
        }
    return;
  }

  // zz 0/1: RoPE pairs (tn2, tn2+2) = dims (d, d+32), d = tn2*16+fr
#pragma unroll
  for (int tn2 = 0; tn2 < 2; ++tn2) {
    const int i = tn2 * 16 + fr;
#pragma unroll
    for (int tm = 0; tm < 8; ++tm)
#pragma unroll
      for (int r = 0; r < 4; ++r) {
        const int m = m_base + tm * 16 + fg * 4 + r;
        const int s = m & (SEQ - 1);
        const size_t bh = (size_t)((m >> 11) * NH + h);
        const float x1 = acc[tm][tn2][r] + bias_s[tn2];
        const float x2 = acc[tm][tn2 + 2][r] + bias_s[tn2 + 2];
        const float2 sc = sctab[(s << 5) + i];
        const float sv = sc.x, cv = sc.y;
        const float o1 = (x1 * sv - x2 * cv) * scale;
        const float o2 = (x2 * sv + x1 * cv) * scale;
        const int d1 = i, d2 = i + 32;
#pragma unroll
        for (int e = 0; e < 2; ++e) {
          const int d = e ? d2 : d1;
          const float ov = e ? o2 : o1;
          const int ks = d >> 5, fgq = (d >> 3) & 3, j = d & 7;
          size_t pos;
          if (zz == 0) {
            const int qt = s >> 5, mm = (s >> 4) & 1, fr2 = s & 15;
            pos = ((((bh * 64 + qt) * 2 + mm) * 2 + ks) * 64 + fgq * 16 + fr2) * 8 + j;
          } else {
            const int ktl = s >> 6, jt = (s >> 4) & 3, fr2 = s & 15;
            pos = ((((bh * 32 + ktl) * 4 + jt) * 2 + ks) * 64 + fgq * 16 + fr2) * 8 + j;
          }
          out[pos] = f2h(ov);
        }
      }
  }
}

// ---------------------------------------------------------------------------
// Flash attention v3 — R5 structure (plateau ~80 µs; R6 qn-shrink and
// R7/R8 ILP attempts both failed to move it — leave alone).
// Wave owns 64 q-rows (qn=4); per kv-tile (64 keys):
//   scores S^T = mfma16x16x32(K_frag, Q_frag); P: exp2 + pack into half4;
//   PV via K=32 mfma (P8 concat || V swizzle agree on key permutation).
// s_setprio(1) around MFMA clusters. exp2 via raw v_exp_f32 (scores
// bounded). Denominators via v_dot2_f32_f16 on the packed half2 P.
// Epilogue: per-wave LDS transpose -> coalesced 16B ctx stores (fp16
// k-block-major, feeds out-proj GEMM directly).
// ---------------------------------------------------------------------------
__global__ __launch_bounds__(256, 2)
void flash_mfma(const ush* __restrict__ qsw, const ush* __restrict__ ksw,
                const ush* __restrict__ vsw, ush* __restrict__ ctxf) {
  __shared__ __align__(16) ush Tep[4][64][72];
  __shared__ float Lden[4][64];
  const int tid = threadIdx.x;
  const int wave = tid >> 6;
  const int lane = tid & 63;
  const int fr = lane & 15;
  const int fg = lane >> 4;

  // XCD swizzle: all 8 q-blocks of one (b,h) on one XCD
  const int lin = blockIdx.x + 8 * blockIdx.y;     // grid (8, 64)
  const int xcd = lin & 7;
  const int t2  = lin >> 3;
  const int qblk = t2 & 7;
  const int bh   = xcd + 8 * (t2 >> 3);

  const int q0 = qblk * 256 + wave * 64;
  const ush* qp = qsw + ((size_t)bh * 64 + (q0 >> 5)) * 2048;
  const ush* kp = ksw + (size_t)bh * 131072;
  const ush* vp = vsw + (size_t)bh * 131072;

  half8 qf[4][2];
#pragma unroll
  for (int qn = 0; qn < 4; ++qn)
#pragma unroll
    for (int ks = 0; ks < 2; ++ks)
      qf[qn][ks] = *(const half8*)(qp + (qn * 2 + ks) * 512 + lane * 8);

  floatx4 oacc[4][4];
#pragma unroll
  for (int qn = 0; qn < 4; ++qn)
#pragma unroll
    for (int i = 0; i < 4; ++i) oacc[qn][i] = (floatx4){0.f, 0.f, 0.f, 0.f};
  float lsum[4] = {0.f, 0.f, 0.f, 0.f};

  const fp16v2 one2 = {(__fp16)1.0f, (__fp16)1.0f};

#pragma unroll 2
  for (int kt = 0; kt < 32; ++kt) {
    const ush* ktp = kp + kt * 4096;
    const ush* vtp = vp + kt * 4096;

    half8 kf[8], vf[8];
#pragma unroll
    for (int i = 0; i < 8; ++i) kf[i] = *(const half8*)(ktp + i * 512 + lane * 8);
#pragma unroll
    for (int i = 0; i < 8; ++i) vf[i] = *(const half8*)(vtp + i * 512 + lane * 8);

#pragma unroll
    for (int qn = 0; qn < 4; ++qn) {
      // ---- scores S^T[key][q] for this 16-q group
      floatx4 s4[4];
#pragma unroll
      for (int jt = 0; jt < 4; ++jt) s4[jt] = (floatx4){0.f, 0.f, 0.f, 0.f};
      __builtin_amdgcn_s_setprio(1);
#pragma unroll
      for (int ks = 0; ks < 2; ++ks)
#pragma unroll
        for (int jt = 0; jt < 4; ++jt)
          s4[jt] = __builtin_amdgcn_mfma_f32_16x16x32_f16(kf[jt * 2 + ks], qf[qn][ks], s4[jt], 0, 0, 0);
      __builtin_amdgcn_s_setprio(0);

      // ---- p = 2^s (raw v_exp_f32); pack into half4 frags
      half4 P[4];
#pragma unroll
      for (int jt = 0; jt < 4; ++jt) {
        float p0 = __builtin_amdgcn_exp2f(s4[jt][0]);
        float p1 = __builtin_amdgcn_exp2f(s4[jt][1]);
        float p2 = __builtin_amdgcn_exp2f(s4[jt][2]);
        float p3 = __builtin_amdgcn_exp2f(s4[jt][3]);
        PK a, b;
        a.v = __builtin_amdgcn_cvt_pkrtz(p0, p1);
        b.v = __builtin_amdgcn_cvt_pkrtz(p2, p3);
        lsum[qn] = __builtin_amdgcn_fdot2(a.v, one2, lsum[qn], false);
        lsum[qn] = __builtin_amdgcn_fdot2(b.v, one2, lsum[qn], false);
        PH ph; ph.u[0] = a.u; ph.u[1] = b.u;
        P[jt] = ph.h;
      }

      // ---- PV via K=32 MFMA: oacc[qn][dt] += P8[s2] x V[s2][dt]
      __builtin_amdgcn_s_setprio(1);
#pragma unroll
      for (int s2 = 0; s2 < 2; ++s2) {
        half8 p8 = __builtin_shufflevector(P[s2 * 2], P[s2 * 2 + 1], 0, 1, 2, 3, 4, 5, 6, 7);
#pragma unroll
        for (int dt = 0; dt < 4; ++dt)
          oacc[qn][dt] = __builtin_amdgcn_mfma_f32_16x16x32_f16(p8, vf[dt * 2 + s2], oacc[qn][dt], 0, 0, 0);
      }
      __builtin_amdgcn_s_setprio(0);
    }
  }

  // ---- denominators: reduce over key-quads, broadcast via wave-private LDS
#pragma unroll
  for (int qn = 0; qn < 4; ++qn) {
    lsum[qn] += __shfl_xor(lsum[qn], 16);
    lsum[qn] += __shfl_xor(lsum[qn], 32);
    Lden[wave][qn * 16 + fr] = lsum[qn];
  }

  // ---- epilogue: wave-private LDS transpose -> coalesced 16B stores.
  // ctx fp16 k-block-major [(kdim/8)][MROWS][8]
  const int b = bh >> 4, h = bh & 15;
#pragma unroll
  for (int qn = 0; qn < 4; ++qn)
#pragma unroll
    for (int r = 0; r < 4; ++r) {
      const float inv = 1.0f / Lden[wave][qn * 16 + fg * 4 + r];
#pragma unroll
      for (int dt = 0; dt < 4; ++dt)
        Tep[wave][qn * 16 + fg * 4 + r][dt * 16 + fr] = f2h(oacc[qn][dt][r] * inv);
    }
  // no barrier needed: Tep is wave-private, DS ops are in-order per wave
  const size_t mrow0 = (size_t)b * SEQ + q0;
  const int kb = lane >> 3;
#pragma unroll
  for (int i = 0; i < 8; ++i) {
    const int q = (lane & 7) + i * 8;
    short8 v = *(const short8*)&Tep[wave][q][kb * 8];
    *(short8*)(ctxf + ((size_t)(h * 8 + kb) * MROWS + mrow0 + q) * 8) = v;
  }
}

// ---------------------------------------------------------------------------
extern "C" void kernel_launch(void* const* d_in, const int* in_sizes, int n_in,
                              void* d_out, int out_size, void* d_ws, size_t ws_size,
                              hipStream_t stream) {
  const float* hs = (const float*)d_in[0];
  const float* Wq = (const float*)d_in[1];
  const float* bq = (const float*)d_in[2];
  const float* Wk = (const float*)d_in[3];
  const float* bk = (const float*)d_in[4];
  const float* Wv = (const float*)d_in[5];
  const float* bv = (const float*)d_in[6];
  const float* Wo = (const float*)d_in[7];
  const float* bo = (const float*)d_in[8];

  ush* qsw  = (ush*)d_ws;                  // 16 MB  frag-swizzled Q (fp16)
  ush* ksw  = qsw + QKV_U16;               // 16 MB  frag-swizzled K
  ush* vsw  = ksw + QKV_U16;               // 16 MB  frag-swizzled V^T (K-frag order)
  ush* hsf  = vsw + QKV_U16;               // 16 MB  hs fp16 k-block-major
  ush* ctxf = hsf + QKV_U16;               // 16 MB  ctx fp16 k-block-major
  ush* Wf4  = ctxf + QKV_U16;              // 8 MB   W fp16 (q,k,v,o)
  float2* sctab = (float2*)(Wf4 + 4 * DMODEL * DMODEL);  // 512 KB sin/cos

  const size_t WS = (size_t)DMODEL * DMODEL;

  cvt_w4<<<dim3(32, 16, 4), 256, 0, stream>>>(Wq, Wk, Wv, Wo, Wf4, sctab);
  cvt_kb<<<dim3(32, 128), 256, 0, stream>>>(hs, hsf, MROWS);

  // Fused Q+K+V projection: grid x = 3 weight panels x 8 n-blocks; BM=256
  gemm_f16<1><<<dim3(24, 32), 256, 0, stream>>>(hsf, Wf4, bq, bk, bv,
                                                qsw, ksw, vsw, sctab);

  flash_mfma<<<dim3(8, BH), 256, 0, stream>>>(qsw, ksw, vsw, ctxf);

  // Out-projection: BM=256, grid (8,32)
  gemm_f16<0><<<dim3(8, 32), 256, 0, stream>>>(ctxf, Wf4 + 3 * WS, bo, nullptr, nullptr,
                                               d_out, nullptr, nullptr, sctab);
}

// Round 10
// 270.956 us; speedup vs baseline: 1.0091x; 1.0091x over previous
//
#include <hip/hip_runtime.h>
#include <math.h>

#define SEQ 2048
#define DMODEL 1024
#define NH 16
#define HD 64
#define BH 64                      // B*NH
#define MROWS 8192                 // B*SEQ
#define QKV_U16 8388608            // BH*SEQ*HD elements (== MROWS*DMODEL)
#define LOG2E 1.4426950408889634f

typedef __attribute__((ext_vector_type(8))) _Float16 half8;
typedef __attribute__((ext_vector_type(4))) _Float16 half4;
typedef __attribute__((ext_vector_type(2))) __fp16 fp16v2;
typedef __attribute__((ext_vector_type(8))) short short8;
typedef __attribute__((ext_vector_type(4))) float floatx4;
typedef unsigned short ush;

union FH { _Float16 h; ush u; };
union PK { fp16v2 v; unsigned u; };
union PH { unsigned u[2]; half4 h; };

__device__ inline ush f2h(float x) { FH c; c.h = (_Float16)x; return c.u; }

// global -> LDS direct DMA, 16B per lane. LDS dest must be wave-uniform;
// HW writes lane i at ldsbase + i*16 (m104/m108). Global addr is per-lane.
__device__ inline void glds16(const ush* g, ush* l) {
  __builtin_amdgcn_global_load_lds((const __attribute__((address_space(1))) void*)g,
                                   (__attribute__((address_space(3))) void*)l, 16, 0, 0);
}

// ---------------------------------------------------------------------------
// Convert fp32 [M][1024] -> fp16 k-block-major: dst[(k/8)][M][8].
// ---------------------------------------------------------------------------
__global__ __launch_bounds__(256)
void cvt_kb(const float* __restrict__ src, ush* __restrict__ dst, int M) {
  __shared__ float T[64][33];
  const int t = threadIdx.x;
  const int k0 = blockIdx.x * 32, m0 = blockIdx.y * 64;
  {
    int row = t >> 2, c = (t & 3) * 8;
    const float* sp = src + (size_t)(m0 + row) * DMODEL + k0 + c;
    float4 x0 = *(const float4*)sp;
    float4 x1 = *(const float4*)(sp + 4);
    float xs[8] = {x0.x, x0.y, x0.z, x0.w, x1.x, x1.y, x1.z, x1.w};
#pragma unroll
    for (int j = 0; j < 8; ++j) T[row][c + j] = xs[j];
  }
  __syncthreads();
  const int ml = t & 63, kbl = t >> 6;
  short8 h8;
#pragma unroll
  for (int j = 0; j < 8; ++j) h8[j] = (short)f2h(T[ml][kbl * 8 + j]);
  *(short8*)(dst + ((size_t)(k0 / 8 + kbl) * M + m0 + ml) * 8) = h8;
}

// 4 weight matrices in one launch (blockIdx.z selects); z==3 plane also
// fills the RoPE sin/cos table (512 blocks cover the 65536 entries).
__global__ __launch_bounds__(256)
void cvt_w4(const float* __restrict__ W0, const float* __restrict__ W1,
            const float* __restrict__ W2, const float* __restrict__ W3,
            ush* __restrict__ dst, float2* __restrict__ tab) {
  __shared__ float T[64][33];
  const int z = blockIdx.z;
  if (z == 3) {
    const int idx = (blockIdx.y * 32 + blockIdx.x) * 256 + threadIdx.x;
    if (idx < 65536) {
      const int s = idx >> 5, i = idx & 31;
      const float f = (float)pow(10000.0, -(double)i / 32.0);
      const float ang = (float)s * f;
      tab[idx] = make_float2(sinf(ang), cosf(ang));
    }
  }
  const float* src = (z == 0) ? W0 : (z == 1) ? W1 : (z == 2) ? W2 : W3;
  ush* dz = dst + (size_t)z * DMODEL * DMODEL;
  const int t = threadIdx.x;
  const int k0 = blockIdx.x * 32, m0 = blockIdx.y * 64;
  {
    int row = t >> 2, c = (t & 3) * 8;
    const float* sp = src + (size_t)(m0 + row) * DMODEL + k0 + c;
    float4 x0 = *(const float4*)sp;
    float4 x1 = *(const float4*)(sp + 4);
    float xs[8] = {x0.x, x0.y, x0.z, x0.w, x1.x, x1.y, x1.z, x1.w};
#pragma unroll
    for (int j = 0; j < 8; ++j) T[row][c + j] = xs[j];
  }
  __syncthreads();
  const int ml = t & 63, kbl = t >> 6;
  short8 h8;
#pragma unroll
  for (int j = 0; j < 8; ++j) h8[j] = (short)f2h(T[ml][kbl * 8 + j]);
  *(short8*)(dz + ((size_t)(k0 / 8 + kbl) * DMODEL + m0 + ml) * 8) = h8;
}

// ---------------------------------------------------------------------------
// fp16 MFMA GEMM (NT), LDS-staged with T4 counted-vmcnt pipeline.
// R8 configuration (best: 265.8 total). R9 lesson: BM=256 (2x MFMA per
// barrier) was NEUTRAL on QKV and hurt out-proj residency — barrier
// amortization is NOT the binding constraint at this plateau (~670 TF);
// reverted. The next GEMM step would be the full 8-phase 256²/8-wave
// template, a different-template port (128²/4-wave 8ph is unreproduced).
//   - 3 LDS buffers (48 KB -> 3 blocks/CU); stage(t+2) at iter t.
//   - per-wave counted s_waitcnt vmcnt(4) (4 own glds16 per tile) + raw
//     s_barrier; loads for t+2 stay in flight ACROSS the barrier; vmcnt(0)
//     only at the tail. (R6-R8: verified correct.)
// Geometry: BM=128, BN=128, BK=32; 4 waves, wave = 64m x 64n (acc 4x4).
// QKV==1: Q,K,V fused, grid (24,64). QKV==0: out-proj, grid (8,64).
// Staging: wave-uniform LDS base + lane*16 (m104); contiguous 1KB/wave.
// RoPE via precomputed sin/cos table (reference has sin/cos names swapped:
// new1 = x1*sin - x2*cos ; new2 = x2*sin + x1*cos).
// ---------------------------------------------------------------------------
template<int QKV>
__global__ __launch_bounds__(256, 3)
void gemm_f16(const ush* __restrict__ A, const ush* __restrict__ W0,
              const float* __restrict__ b0, const float* __restrict__ b1,
              const float* __restrict__ b2, void* __restrict__ out0,
              void* __restrict__ out1, void* __restrict__ out2,
              const float2* __restrict__ sctab) {
  constexpr int NT = 32;                   // K / BK(=32) tiles
  __shared__ ush SA[3][4096];              // 4 kb x 128 rows x 8 = 8 KB each
  __shared__ ush SW[3][4096];
  const int tid  = threadIdx.x;
  const int wave = tid >> 6;
  const int lane = tid & 63;
  const int fr = lane & 15;
  const int fg = lane >> 4;
  const int wm = wave & 1;
  const int wn = wave >> 1;

  const int zz = QKV ? (blockIdx.x >> 3) : 3;         // 0=Q 1=K 2=V 3=out
  const int nx = QKV ? (blockIdx.x & 7) : blockIdx.x;
  const int m0 = blockIdx.y * 128;
  const int n0 = nx * 128;
  const int m_base = m0 + wm * 64;
  const int n_base = n0 + wn * 64;

  const ush* W = W0 + (size_t)(QKV ? zz : 0) * (DMODEL * DMODEL);
  const float* bias = QKV ? (zz == 0 ? b0 : zz == 1 ? b1 : b2) : b0;
  void* outp = QKV ? (zz == 0 ? out0 : zz == 1 ? out1 : out2) : out0;
  const float scale = (QKV && zz == 0) ? 0.125f * LOG2E : 1.0f;

  floatx4 acc[4][4];
#pragma unroll
  for (int i = 0; i < 4; ++i)
#pragma unroll
    for (int j = 0; j < 4; ++j) acc[i][j] = (floatx4){0.f, 0.f, 0.f, 0.f};

  // stage one BK=32 tile (4 k-blocks) into buffer b: 4 glds16 per wave
  auto stage = [&](int b, int kt) {
    const int kb0 = kt * 4;
#pragma unroll
    for (int p = 0; p < 2; ++p) {
      const int c = p * 256 + wave * 64;            // chunk = one row's 16B
      const int kb = c >> 7, r0 = c & 127;
      glds16(A + (size_t)(kb0 + kb) * (MROWS * 8) + (size_t)(m0 + r0 + lane) * 8,
             &SA[b][(size_t)c * 8]);
      glds16(W + (size_t)(kb0 + kb) * (DMODEL * 8) + (size_t)(n0 + r0 + lane) * 8,
             &SW[b][(size_t)c * 8]);
    }
  };

  auto compute = [&](int b) {
    const int kbl = fg;                          // 4 k-blocks = BK 32
    half8 ah[4], wh[4];
#pragma unroll
    for (int tm = 0; tm < 4; ++tm)
      ah[tm] = *(const half8*)&SA[b][(size_t)(kbl * 128 + wm * 64 + tm * 16 + fr) * 8];
#pragma unroll
    for (int tn = 0; tn < 4; ++tn)
      wh[tn] = *(const half8*)&SW[b][(size_t)(kbl * 128 + wn * 64 + tn * 16 + fr) * 8];
#pragma unroll
    for (int tm = 0; tm < 4; ++tm)
#pragma unroll
      for (int tn = 0; tn < 4; ++tn)
        acc[tm][tn] = __builtin_amdgcn_mfma_f32_16x16x32_f16(ah[tm], wh[tn], acc[tm][tn], 0, 0, 0);
  };

  // ---- prologue: 2 tiles in flight, wait only the oldest
  stage(0, 0);
  stage(1, 1);
  asm volatile("s_waitcnt vmcnt(4)" ::: "memory");
  __builtin_amdgcn_s_barrier();
  __builtin_amdgcn_sched_barrier(0);

  int bc = 0;
  for (int t = 0; t < NT; ++t) {
    if (t + 2 < NT) {
      int bs = bc + 2; if (bs >= 3) bs -= 3;
      stage(bs, t + 2);
    }
    compute(bc);
    if (t + 1 < NT) {
      if (t + 2 < NT) {
        asm volatile("s_waitcnt vmcnt(4)" ::: "memory");
      } else {
        asm volatile("s_waitcnt vmcnt(0)" ::: "memory");
      }
      __builtin_amdgcn_s_barrier();
      __builtin_amdgcn_sched_barrier(0);
    }
    ++bc; if (bc == 3) bc = 0;
  }

  float bias_s[4];
#pragma unroll
  for (int tn = 0; tn < 4; ++tn) bias_s[tn] = bias[n_base + tn * 16 + fr];

  if (!QKV) {                           // out-proj: fp32 row-major
#pragma unroll
    for (int tm = 0; tm < 4; ++tm)
#pragma unroll
      for (int tn = 0; tn < 4; ++tn)
#pragma unroll
        for (int r = 0; r < 4; ++r) {
          const int m = m_base + tm * 16 + fg * 4 + r;
          const int n = n_base + tn * 16 + fr;
          ((float*)outp)[(size_t)m * DMODEL + n] = acc[tm][tn][r] + bias_s[tn];
        }
    return;
  }

  const int h = (n_base >> 6) & 15;
  ush* out = (ush*)outp;

  if (zz == 2) {                        // V: no rope, K-frag layout for PV
#pragma unroll
    for (int tm = 0; tm < 4; ++tm)
#pragma unroll
      for (int tn = 0; tn < 4; ++tn)
#pragma unroll
        for (int r = 0; r < 4; ++r) {
          const int m = m_base + tm * 16 + fg * 4 + r;
          const int s = m & (SEQ - 1);
          const size_t bh = (size_t)((m >> 11) * NH + h);
          const int d = tn * 16 + fr;
          const int k6 = s & 63, ktl = s >> 6;
          const int s2 = k6 >> 5;
          const int jj = ((k6 >> 4) & 1) * 4 + (k6 & 3);
          const int fgv = (k6 >> 2) & 3;
          const int dt = d >> 4, frv = d & 15;
          size_t pos = ((((bh * 32 + ktl) * 4 + dt) * 2 + s2) * 64 + fgv * 16 + frv) * 8 + jj;
          out[pos] = f2h(acc[tm][tn][r] + bias_s[tn]);
        }
    return;
  }

  // zz 0/1: RoPE pairs (tn2, tn2+2) = dims (d, d+32), d = tn2*16+fr
#pragma unroll
  for (int tn2 = 0; tn2 < 2; ++tn2) {
    const int i = tn2 * 16 + fr;
#pragma unroll
    for (int tm = 0; tm < 4; ++tm)
#pragma unroll
      for (int r = 0; r < 4; ++r) {
        const int m = m_base + tm * 16 + fg * 4 + r;
        const int s = m & (SEQ - 1);
        const size_t bh = (size_t)((m >> 11) * NH + h);
        const float x1 = acc[tm][tn2][r] + bias_s[tn2];
        const float x2 = acc[tm][tn2 + 2][r] + bias_s[tn2 + 2];
        const float2 sc = sctab[(s << 5) + i];
        const float sv = sc.x, cv = sc.y;
        const float o1 = (x1 * sv - x2 * cv) * scale;
        const float o2 = (x2 * sv + x1 * cv) * scale;
        const int d1 = i, d2 = i + 32;
#pragma unroll
        for (int e = 0; e < 2; ++e) {
          const int d = e ? d2 : d1;
          const float ov = e ? o2 : o1;
          const int ks = d >> 5, fgq = (d >> 3) & 3, j = d & 7;
          size_t pos;
          if (zz == 0) {
            const int qt = s >> 5, mm = (s >> 4) & 1, fr2 = s & 15;
            pos = ((((bh * 64 + qt) * 2 + mm) * 2 + ks) * 64 + fgq * 16 + fr2) * 8 + j;
          } else {
            const int ktl = s >> 6, jt = (s >> 4) & 3, fr2 = s & 15;
            pos = ((((bh * 32 + ktl) * 4 + jt) * 2 + ks) * 64 + fgq * 16 + fr2) * 8 + j;
          }
          out[pos] = f2h(ov);
        }
      }
  }
}

// ---------------------------------------------------------------------------
// Flash attention v4: block-shared K/V via LDS (R9 theory: the 4 waves of a
// block all loaded the IDENTICAL 16 KB K/V tile from L2 — 64 KB/block/tile;
// per-tile cycle budget showed MFMA+VALU+L2 were ADDITIVE ~6000 cyc, with
// the L2 stream ~2300 cyc of it). Now: one wave-split glds16 stage (16 KB
// per block per tile, 4 chunks/wave), T4-counted vmcnt(4) + s_barrier,
// 2 LDS buffers; waves ds_read fragments (stride-16B, conflict-free — same
// pattern as the GEMM which shows 0 conflicts). L2 traffic / 4.
// LDS: staging [2][8192] (32 KB) ALIASED with epilogue Tep (36.9 KB; only
// live after the loop's final barrier) -> 37 KB total, occupancy unchanged.
// Compute per kv-tile unchanged from the R5 champion (qn=4, K=32 PV,
// raw exp2, fdot2 denominators, setprio around MFMA).
// ---------------------------------------------------------------------------
__global__ __launch_bounds__(256, 2)
void flash_mfma(const ush* __restrict__ qsw, const ush* __restrict__ ksw,
                const ush* __restrict__ vsw, ush* __restrict__ ctxf) {
  // max(2*8192 staging, 4*64*72 Tep) = 18432 ush = 36.9 KB
  __shared__ __align__(16) ush SMEM[18432];
  __shared__ float Lden[4][64];
  const int tid = threadIdx.x;
  const int wave = tid >> 6;
  const int lane = tid & 63;
  const int fr = lane & 15;
  const int fg = lane >> 4;

  // XCD swizzle: all 8 q-blocks of one (b,h) on one XCD
  const int lin = blockIdx.x + 8 * blockIdx.y;     // grid (8, 64)
  const int xcd = lin & 7;
  const int t2  = lin >> 3;
  const int qblk = t2 & 7;
  const int bh   = xcd + 8 * (t2 >> 3);

  const int q0 = qblk * 256 + wave * 64;
  const ush* qp = qsw + ((size_t)bh * 64 + (q0 >> 5)) * 2048;
  const ush* kp = ksw + (size_t)bh * 131072;
  const ush* vp = vsw + (size_t)bh * 131072;

  half8 qf[4][2];
#pragma unroll
  for (int qn = 0; qn < 4; ++qn)
#pragma unroll
    for (int ks = 0; ks < 2; ++ks)
      qf[qn][ks] = *(const half8*)(qp + (qn * 2 + ks) * 512 + lane * 8);

  floatx4 oacc[4][4];
#pragma unroll
  for (int qn = 0; qn < 4; ++qn)
#pragma unroll
    for (int i = 0; i < 4; ++i) oacc[qn][i] = (floatx4){0.f, 0.f, 0.f, 0.f};
  float lsum[4] = {0.f, 0.f, 0.f, 0.f};

  const fp16v2 one2 = {(__fp16)1.0f, (__fp16)1.0f};

  // stage one 64-key K/V tile (16 KB) into buffer b: 4 chunks per wave.
  // K tile (8 KB) is contiguous at kp+kt*4096; V likewise. Chunk c in
  // [0,16): c<8 -> K chunk c, else V chunk c-8; LDS offset = c*512 either
  // way (K occupies [0,4096), V [4096,8192) of the buffer).
  auto stageKV = [&](int b, int kt) {
#pragma unroll
    for (int j = 0; j < 4; ++j) {
      const int c = j * 4 + wave;                  // wave-uniform
      const ush* g = (c < 8) ? (kp + kt * 4096 + c * 512)
                             : (vp + kt * 4096 + (c - 8) * 512);
      glds16(g + lane * 8, &SMEM[(size_t)b * 8192 + c * 512]);
    }
  };

  stageKV(0, 0);
  stageKV(1, 1);

  for (int kt = 0; kt < 32; ++kt) {
    const int cur = kt & 1;
    const ush* kb = &SMEM[(size_t)cur * 8192];
    if (kt + 1 < 32) asm volatile("s_waitcnt vmcnt(4)" ::: "memory");
    else             asm volatile("s_waitcnt vmcnt(0)" ::: "memory");
    __builtin_amdgcn_s_barrier();
    __builtin_amdgcn_sched_barrier(0);

    half8 kf[8], vf[8];
#pragma unroll
    for (int i = 0; i < 8; ++i) kf[i] = *(const half8*)(kb + i * 512 + lane * 8);
#pragma unroll
    for (int i = 0; i < 8; ++i) vf[i] = *(const half8*)(kb + 4096 + i * 512 + lane * 8);

#pragma unroll
    for (int qn = 0; qn < 4; ++qn) {
      // ---- scores S^T[key][q] for this 16-q group
      floatx4 s4[4];
#pragma unroll
      for (int jt = 0; jt < 4; ++jt) s4[jt] = (floatx4){0.f, 0.f, 0.f, 0.f};
      __builtin_amdgcn_s_setprio(1);
#pragma unroll
      for (int ks = 0; ks < 2; ++ks)
#pragma unroll
        for (int jt = 0; jt < 4; ++jt)
          s4[jt] = __builtin_amdgcn_mfma_f32_16x16x32_f16(kf[jt * 2 + ks], qf[qn][ks], s4[jt], 0, 0, 0);
      __builtin_amdgcn_s_setprio(0);

      // ---- p = 2^s (raw v_exp_f32); pack into half4 frags
      half4 P[4];
#pragma unroll
      for (int jt = 0; jt < 4; ++jt) {
        float p0 = __builtin_amdgcn_exp2f(s4[jt][0]);
        float p1 = __builtin_amdgcn_exp2f(s4[jt][1]);
        float p2 = __builtin_amdgcn_exp2f(s4[jt][2]);
        float p3 = __builtin_amdgcn_exp2f(s4[jt][3]);
        PK a, b;
        a.v = __builtin_amdgcn_cvt_pkrtz(p0, p1);
        b.v = __builtin_amdgcn_cvt_pkrtz(p2, p3);
        lsum[qn] = __builtin_amdgcn_fdot2(a.v, one2, lsum[qn], false);
        lsum[qn] = __builtin_amdgcn_fdot2(b.v, one2, lsum[qn], false);
        PH ph; ph.u[0] = a.u; ph.u[1] = b.u;
        P[jt] = ph.h;
      }

      // ---- PV via K=32 MFMA: oacc[qn][dt] += P8[s2] x V[s2][dt]
      __builtin_amdgcn_s_setprio(1);
#pragma unroll
      for (int s2 = 0; s2 < 2; ++s2) {
        half8 p8 = __builtin_shufflevector(P[s2 * 2], P[s2 * 2 + 1], 0, 1, 2, 3, 4, 5, 6, 7);
#pragma unroll
        for (int dt = 0; dt < 4; ++dt)
          oacc[qn][dt] = __builtin_amdgcn_mfma_f32_16x16x32_f16(p8, vf[dt * 2 + s2], oacc[qn][dt], 0, 0, 0);
      }
      __builtin_amdgcn_s_setprio(0);
    }

    __builtin_amdgcn_s_barrier();      // all waves done reading buf cur
    __builtin_amdgcn_sched_barrier(0);
    if (kt + 2 < 32) stageKV(cur, kt + 2);   // cur now free -> stage kt+2
  }
  // final barrier above also fences the loop before Tep aliases the buffers

  // ---- denominators: reduce over key-quads, broadcast via wave-private LDS
#pragma unroll
  for (int qn = 0; qn < 4; ++qn) {
    lsum[qn] += __shfl_xor(lsum[qn], 16);
    lsum[qn] += __shfl_xor(lsum[qn], 32);
    Lden[wave][qn * 16 + fr] = lsum[qn];
  }

  // ---- epilogue: wave-private LDS transpose -> coalesced 16B stores.
  // Tep aliased onto SMEM: Tep[w][q][d] = SMEM[w*4608 + q*72 + d]
  const int b = bh >> 4, h = bh & 15;
  ush* tep = &SMEM[(size_t)wave * 4608];
#pragma unroll
  for (int qn = 0; qn < 4; ++qn)
#pragma unroll
    for (int r = 0; r < 4; ++r) {
      const float inv = 1.0f / Lden[wave][qn * 16 + fg * 4 + r];
#pragma unroll
      for (int dt = 0; dt < 4; ++dt)
        tep[(qn * 16 + fg * 4 + r) * 72 + dt * 16 + fr] = f2h(oacc[qn][dt][r] * inv);
    }
  // no barrier needed: Tep slice is wave-private, DS ops in-order per wave
  const size_t mrow0 = (size_t)b * SEQ + q0;
  const int kb2 = lane >> 3;
#pragma unroll
  for (int i = 0; i < 8; ++i) {
    const int q = (lane & 7) + i * 8;
    short8 v = *(const short8*)&tep[q * 72 + kb2 * 8];
    *(short8*)(ctxf + ((size_t)(h * 8 + kb2) * MROWS + mrow0 + q) * 8) = v;
  }
}

// ---------------------------------------------------------------------------
extern "C" void kernel_launch(void* const* d_in, const int* in_sizes, int n_in,
                              void* d_out, int out_size, void* d_ws, size_t ws_size,
                              hipStream_t stream) {
  const float* hs = (const float*)d_in[0];
  const float* Wq = (const float*)d_in[1];
  const float* bq = (const float*)d_in[2];
  const float* Wk = (const float*)d_in[3];
  const float* bk = (const float*)d_in[4];
  const float* Wv = (const float*)d_in[5];
  const float* bv = (const float*)d_in[6];
  const float* Wo = (const float*)d_in[7];
  const float* bo = (const float*)d_in[8];

  ush* qsw  = (ush*)d_ws;                  // 16 MB  frag-swizzled Q (fp16)
  ush* ksw  = qsw + QKV_U16;               // 16 MB  frag-swizzled K
  ush* vsw  = ksw + QKV_U16;               // 16 MB  frag-swizzled V^T (K-frag order)
  ush* hsf  = vsw + QKV_U16;               // 16 MB  hs fp16 k-block-major
  ush* ctxf = hsf + QKV_U16;               // 16 MB  ctx fp16 k-block-major
  ush* Wf4  = ctxf + QKV_U16;              // 8 MB   W fp16 (q,k,v,o)
  float2* sctab = (float2*)(Wf4 + 4 * DMODEL * DMODEL);  // 512 KB sin/cos

  const size_t WS = (size_t)DMODEL * DMODEL;

  cvt_w4<<<dim3(32, 16, 4), 256, 0, stream>>>(Wq, Wk, Wv, Wo, Wf4, sctab);
  cvt_kb<<<dim3(32, 128), 256, 0, stream>>>(hs, hsf, MROWS);

  // Fused Q+K+V projection: grid x = 3 weight panels x 8 n-blocks
  gemm_f16<1><<<dim3(24, 64), 256, 0, stream>>>(hsf, Wf4, bq, bk, bv,
                                                qsw, ksw, vsw, sctab);

  flash_mfma<<<dim3(8, BH), 256, 0, stream>>>(qsw, ksw, vsw, ctxf);

  // Out-projection: BM=128 unified tile, grid (8,64)
  gemm_f16<0><<<dim3(8, 64), 256, 0, stream>>>(ctxf, Wf4 + 3 * WS, bo, nullptr, nullptr,
                                               d_out, nullptr, nullptr, sctab);
}

// Round 11
// 260.009 us; speedup vs baseline: 1.0516x; 1.0421x over previous
//
#include <hip/hip_runtime.h>
#include <math.h>

#define SEQ 2048
#define DMODEL 1024
#define NH 16
#define HD 64
#define BH 64                      // B*NH
#define MROWS 8192                 // B*SEQ
#define QKV_U16 8388608            // BH*SEQ*HD elements (== MROWS*DMODEL)
#define LOG2E 1.4426950408889634f

typedef __attribute__((ext_vector_type(8))) _Float16 half8;
typedef __attribute__((ext_vector_type(4))) _Float16 half4;
typedef __attribute__((ext_vector_type(2))) __fp16 fp16v2;
typedef __attribute__((ext_vector_type(8))) short short8;
typedef __attribute__((ext_vector_type(4))) float floatx4;
typedef unsigned short ush;

union FH { _Float16 h; ush u; };
union PK { fp16v2 v; unsigned u; };
union PH { unsigned u[2]; half4 h; };

__device__ inline ush f2h(float x) { FH c; c.h = (_Float16)x; return c.u; }

// global -> LDS direct DMA, 16B per lane. LDS dest must be wave-uniform;
// HW writes lane i at ldsbase + i*16 (m104/m108). Global addr is per-lane.
__device__ inline void glds16(const ush* g, ush* l) {
  __builtin_amdgcn_global_load_lds((const __attribute__((address_space(1))) void*)g,
                                   (__attribute__((address_space(3))) void*)l, 16, 0, 0);
}

// ---------------------------------------------------------------------------
// Convert fp32 [M][1024] -> fp16 k-block-major: dst[(k/8)][M][8].
// ---------------------------------------------------------------------------
__global__ __launch_bounds__(256)
void cvt_kb(const float* __restrict__ src, ush* __restrict__ dst, int M) {
  __shared__ float T[64][33];
  const int t = threadIdx.x;
  const int k0 = blockIdx.x * 32, m0 = blockIdx.y * 64;
  {
    int row = t >> 2, c = (t & 3) * 8;
    const float* sp = src + (size_t)(m0 + row) * DMODEL + k0 + c;
    float4 x0 = *(const float4*)sp;
    float4 x1 = *(const float4*)(sp + 4);
    float xs[8] = {x0.x, x0.y, x0.z, x0.w, x1.x, x1.y, x1.z, x1.w};
#pragma unroll
    for (int j = 0; j < 8; ++j) T[row][c + j] = xs[j];
  }
  __syncthreads();
  const int ml = t & 63, kbl = t >> 6;
  short8 h8;
#pragma unroll
  for (int j = 0; j < 8; ++j) h8[j] = (short)f2h(T[ml][kbl * 8 + j]);
  *(short8*)(dst + ((size_t)(k0 / 8 + kbl) * M + m0 + ml) * 8) = h8;
}

// 4 weight matrices in one launch (blockIdx.z selects); z==3 plane also
// fills the RoPE sin/cos table (512 blocks cover the 65536 entries).
__global__ __launch_bounds__(256)
void cvt_w4(const float* __restrict__ W0, const float* __restrict__ W1,
            const float* __restrict__ W2, const float* __restrict__ W3,
            ush* __restrict__ dst, float2* __restrict__ tab) {
  __shared__ float T[64][33];
  const int z = blockIdx.z;
  if (z == 3) {
    const int idx = (blockIdx.y * 32 + blockIdx.x) * 256 + threadIdx.x;
    if (idx < 65536) {
      const int s = idx >> 5, i = idx & 31;
      const float f = (float)pow(10000.0, -(double)i / 32.0);
      const float ang = (float)s * f;
      tab[idx] = make_float2(sinf(ang), cosf(ang));
    }
  }
  const float* src = (z == 0) ? W0 : (z == 1) ? W1 : (z == 2) ? W2 : W3;
  ush* dz = dst + (size_t)z * DMODEL * DMODEL;
  const int t = threadIdx.x;
  const int k0 = blockIdx.x * 32, m0 = blockIdx.y * 64;
  {
    int row = t >> 2, c = (t & 3) * 8;
    const float* sp = src + (size_t)(m0 + row) * DMODEL + k0 + c;
    float4 x0 = *(const float4*)sp;
    float4 x1 = *(const float4*)(sp + 4);
    float xs[8] = {x0.x, x0.y, x0.z, x0.w, x1.x, x1.y, x1.z, x1.w};
#pragma unroll
    for (int j = 0; j < 8; ++j) T[row][c + j] = xs[j];
  }
  __syncthreads();
  const int ml = t & 63, kbl = t >> 6;
  short8 h8;
#pragma unroll
  for (int j = 0; j < 8; ++j) h8[j] = (short)f2h(T[ml][kbl * 8 + j]);
  *(short8*)(dz + ((size_t)(k0 / 8 + kbl) * DMODEL + m0 + ml) * 8) = h8;
}

// ---------------------------------------------------------------------------
// fp16 MFMA GEMM (NT), phase-split 8-wave schedule (T3+T4 port).
// R9/R10 diagnosis: the 2-barrier-per-tile T4 loop sits at the documented
// 2-phase ceiling (~670 TF) regardless of tile size (BM 256 neutral, R9) —
// the lever is the per-phase interleave, not per-barrier MFMA count.
// Structure (m196/m198/m201 lineage, adapted to k-block-major fp16):
//   512 thr = 8 waves (wm 0..3 x wn 0..1), BM=256 BN=128 BK=64, NT=16.
//   3 LDS buffers (144 KB -> 1 block/CU); per K-tile 2 phases (kh=0/1):
//     {8 ds_read_b128 frags; issue 3 glds16 chunks of tile t+2 into buf
//      (t+2)%3 (never the buffer being read); s_barrier; 16 MFMA under
//      setprio; s_barrier}
//   counted s_waitcnt vmcnt(6) ONCE per K-tile (6 = own loads of one tile;
//   t+2's 6 stay in flight across barriers); vmcnt(0) only at tail.
// Per-wave output 64m x 64n, acc[4][4] -> epilogues UNCHANGED from the
// verified R8 kernel (RoPE table / V K-frag swizzle / fp32 out).
// QKV==1: grid (24,32) = 768 blocks = 3 full rounds. QKV==0: grid (8,32)
// = 256 blocks = exactly 1/CU (fixes out-proj's chronic residency gap).
// ds_read pattern: 16B rows, stride-16B within 16-lane groups -> measured
// 0 bank conflicts on this layout (R5-R10).
// ---------------------------------------------------------------------------
template<int QKV>
__global__ __launch_bounds__(512, 2)
void gemm_f16(const ush* __restrict__ A, const ush* __restrict__ W0,
              const float* __restrict__ b0, const float* __restrict__ b1,
              const float* __restrict__ b2, void* __restrict__ out0,
              void* __restrict__ out1, void* __restrict__ out2,
              const float2* __restrict__ sctab) {
  constexpr int NT = 16;                   // K / BK(=64) tiles
  __shared__ ush SA[3][16384];             // 8 kb x 256 rows x 8 = 32 KB each
  __shared__ ush SW[3][8192];              // 8 kb x 128 rows x 8 = 16 KB each
  const int tid  = threadIdx.x;
  const int wave = tid >> 6;               // 0..7
  const int lane = tid & 63;
  const int fr = lane & 15;
  const int fg = lane >> 4;
  const int wm = wave >> 1;                // 0..3 (m quarter)
  const int wn = wave & 1;                 // 0..1 (n half)

  const int zz = QKV ? (blockIdx.x >> 3) : 3;         // 0=Q 1=K 2=V 3=out
  const int nx = QKV ? (blockIdx.x & 7) : blockIdx.x;
  const int m0 = blockIdx.y * 256;
  const int n0 = nx * 128;
  const int m_base = m0 + wm * 64;
  const int n_base = n0 + wn * 64;

  const ush* W = W0 + (size_t)(QKV ? zz : 0) * (DMODEL * DMODEL);
  const float* bias = QKV ? (zz == 0 ? b0 : zz == 1 ? b1 : b2) : b0;
  void* outp = QKV ? (zz == 0 ? out0 : zz == 1 ? out1 : out2) : out0;
  const float scale = (QKV && zz == 0) ? 0.125f * LOG2E : 1.0f;

  floatx4 acc[4][4];
#pragma unroll
  for (int i = 0; i < 4; ++i)
#pragma unroll
    for (int j = 0; j < 4; ++j) acc[i][j] = (floatx4){0.f, 0.f, 0.f, 0.f};

  // A chunk p (0..3): 512 thr x 16B = 8 KB; c = p*512+wave*64 (uniform/wave)
  auto stageA = [&](int b, int kt, int p) {
    const int c = p * 512 + wave * 64;
    const int kb = c >> 8, r0 = c & 255;
    glds16(A + (size_t)(kt * 8 + kb) * (MROWS * 8) + (size_t)(m0 + r0 + lane) * 8,
           &SA[b][(size_t)c * 8]);
  };
  // B chunk p (0..1)
  auto stageB = [&](int b, int kt, int p) {
    const int c = p * 512 + wave * 64;
    const int kb = c >> 7, r0 = c & 127;
    glds16(W + (size_t)(kt * 8 + kb) * (DMODEL * 8) + (size_t)(n0 + r0 + lane) * 8,
           &SW[b][(size_t)c * 8]);
  };
  auto stageAll = [&](int b, int kt) {
    stageA(b, kt, 0); stageA(b, kt, 1); stageA(b, kt, 2); stageA(b, kt, 3);
    stageB(b, kt, 0); stageB(b, kt, 1);
  };

  // one phase: ds_read kh-half frags, issue 3 prefetch chunks, barrier,
  // 16 MFMA under setprio. (which=0: A0-2 of t2; which=1: A3,B0,B1)
  auto doPhase = [&](int b, int kh, int b2, int t2, int which) {
    const int kbl = kh * 4 + fg;
    half8 ah[4], wh[4];
#pragma unroll
    for (int tm = 0; tm < 4; ++tm)
      ah[tm] = *(const half8*)&SA[b][(size_t)(kbl * 256 + wm * 64 + tm * 16 + fr) * 8];
#pragma unroll
    for (int tn = 0; tn < 4; ++tn)
      wh[tn] = *(const half8*)&SW[b][(size_t)(kbl * 128 + wn * 64 + tn * 16 + fr) * 8];
    if (which == 0 && t2 < NT) { stageA(b2, t2, 0); stageA(b2, t2, 1); stageA(b2, t2, 2); }
    if (which == 1 && t2 < NT) { stageA(b2, t2, 3); stageB(b2, t2, 0); stageB(b2, t2, 1); }
    __builtin_amdgcn_s_barrier();
    __builtin_amdgcn_sched_barrier(0);
    __builtin_amdgcn_s_setprio(1);
#pragma unroll
    for (int tm = 0; tm < 4; ++tm)
#pragma unroll
      for (int tn = 0; tn < 4; ++tn)
        acc[tm][tn] = __builtin_amdgcn_mfma_f32_16x16x32_f16(ah[tm], wh[tn], acc[tm][tn], 0, 0, 0);
    __builtin_amdgcn_s_setprio(0);
  };

  // ---- prologue: 2 tiles in flight, wait only the oldest (6 = 1 tile)
  stageAll(0, 0);
  stageAll(1, 1);
  asm volatile("s_waitcnt vmcnt(6)" ::: "memory");
  __builtin_amdgcn_s_barrier();
  __builtin_amdgcn_sched_barrier(0);

  int bc = 0;
  for (int t = 0; t < NT; ++t) {
    int b2 = bc + 2; if (b2 >= 3) b2 -= 3;
    doPhase(bc, 0, b2, t + 2, 0);        // phase 1 (kh=0)
    __builtin_amdgcn_s_barrier();        // phase boundary
    __builtin_amdgcn_sched_barrier(0);
    doPhase(bc, 1, b2, t + 2, 1);        // phase 2 (kh=1)
    if (t + 1 < NT) {                    // tile-end: next tile readiness
      if (t + 2 < NT) asm volatile("s_waitcnt vmcnt(6)" ::: "memory");
      else            asm volatile("s_waitcnt vmcnt(0)" ::: "memory");
      __builtin_amdgcn_s_barrier();
      __builtin_amdgcn_sched_barrier(0);
    }
    ++bc; if (bc == 3) bc = 0;
  }

  float bias_s[4];
#pragma unroll
  for (int tn = 0; tn < 4; ++tn) bias_s[tn] = bias[n_base + tn * 16 + fr];

  if (!QKV) {                           // out-proj: fp32 row-major
#pragma unroll
    for (int tm = 0; tm < 4; ++tm)
#pragma unroll
      for (int tn = 0; tn < 4; ++tn)
#pragma unroll
        for (int r = 0; r < 4; ++r) {
          const int m = m_base + tm * 16 + fg * 4 + r;
          const int n = n_base + tn * 16 + fr;
          ((float*)outp)[(size_t)m * DMODEL + n] = acc[tm][tn][r] + bias_s[tn];
        }
    return;
  }

  const int h = (n_base >> 6) & 15;
  ush* out = (ush*)outp;

  if (zz == 2) {                        // V: no rope, K-frag layout for PV
#pragma unroll
    for (int tm = 0; tm < 4; ++tm)
#pragma unroll
      for (int tn = 0; tn < 4; ++tn)
#pragma unroll
        for (int r = 0; r < 4; ++r) {
          const int m = m_base + tm * 16 + fg * 4 + r;
          const int s = m & (SEQ - 1);
          const size_t bh = (size_t)((m >> 11) * NH + h);
          const int d = tn * 16 + fr;
          const int k6 = s & 63, ktl = s >> 6;
          const int s2 = k6 >> 5;
          const int jj = ((k6 >> 4) & 1) * 4 + (k6 & 3);
          const int fgv = (k6 >> 2) & 3;
          const int dt = d >> 4, frv = d & 15;
          size_t pos = ((((bh * 32 + ktl) * 4 + dt) * 2 + s2) * 64 + fgv * 16 + frv) * 8 + jj;
          out[pos] = f2h(acc[tm][tn][r] + bias_s[tn]);
        }
    return;
  }

  // zz 0/1: RoPE pairs (tn2, tn2+2) = dims (d, d+32), d = tn2*16+fr
#pragma unroll
  for (int tn2 = 0; tn2 < 2; ++tn2) {
    const int i = tn2 * 16 + fr;
#pragma unroll
    for (int tm = 0; tm < 4; ++tm)
#pragma unroll
      for (int r = 0; r < 4; ++r) {
        const int m = m_base + tm * 16 + fg * 4 + r;
        const int s = m & (SEQ - 1);
        const size_t bh = (size_t)((m >> 11) * NH + h);
        const float x1 = acc[tm][tn2][r] + bias_s[tn2];
        const float x2 = acc[tm][tn2 + 2][r] + bias_s[tn2 + 2];
        const float2 sc = sctab[(s << 5) + i];
        const float sv = sc.x, cv = sc.y;
        const float o1 = (x1 * sv - x2 * cv) * scale;
        const float o2 = (x2 * sv + x1 * cv) * scale;
        const int d1 = i, d2 = i + 32;
#pragma unroll
        for (int e = 0; e < 2; ++e) {
          const int d = e ? d2 : d1;
          const float ov = e ? o2 : o1;
          const int ks = d >> 5, fgq = (d >> 3) & 3, j = d & 7;
          size_t pos;
          if (zz == 0) {
            const int qt = s >> 5, mm = (s >> 4) & 1, fr2 = s & 15;
            pos = ((((bh * 64 + qt) * 2 + mm) * 2 + ks) * 64 + fgq * 16 + fr2) * 8 + j;
          } else {
            const int ktl = s >> 6, jt = (s >> 4) & 3, fr2 = s & 15;
            pos = ((((bh * 32 + ktl) * 4 + jt) * 2 + ks) * 64 + fgq * 16 + fr2) * 8 + j;
          }
          out[pos] = f2h(ov);
        }
      }
  }
}

// ---------------------------------------------------------------------------
// Flash attention v3 — R8 configuration verbatim (part of the 265.8 µs
// champion; ~80 µs plateau). R6 qn-shrink, R8 unroll and R10 LDS-share all
// failed to move it — limiter is the dependent QK->exp2->PV chain at 2
// waves/SIMD; parked.
// Wave owns 64 q-rows (qn=4); per kv-tile (64 keys):
//   scores S^T = mfma16x16x32(K_frag, Q_frag); P: exp2 + pack into half4;
//   PV via K=32 mfma (P8 concat || V swizzle agree on key permutation).
// s_setprio(1) around MFMA clusters. exp2 via raw v_exp_f32 (scores
// bounded). Denominators via v_dot2_f32_f16 on the packed half2 P.
// Epilogue: per-wave LDS transpose -> coalesced 16B ctx stores (fp16
// k-block-major, feeds out-proj GEMM directly).
// ---------------------------------------------------------------------------
__global__ __launch_bounds__(256, 2)
void flash_mfma(const ush* __restrict__ qsw, const ush* __restrict__ ksw,
                const ush* __restrict__ vsw, ush* __restrict__ ctxf) {
  __shared__ __align__(16) ush Tep[4][64][72];
  __shared__ float Lden[4][64];
  const int tid = threadIdx.x;
  const int wave = tid >> 6;
  const int lane = tid & 63;
  const int fr = lane & 15;
  const int fg = lane >> 4;

  // XCD swizzle: all 8 q-blocks of one (b,h) on one XCD
  const int lin = blockIdx.x + 8 * blockIdx.y;     // grid (8, 64)
  const int xcd = lin & 7;
  const int t2  = lin >> 3;
  const int qblk = t2 & 7;
  const int bh   = xcd + 8 * (t2 >> 3);

  const int q0 = qblk * 256 + wave * 64;
  const ush* qp = qsw + ((size_t)bh * 64 + (q0 >> 5)) * 2048;
  const ush* kp = ksw + (size_t)bh * 131072;
  const ush* vp = vsw + (size_t)bh * 131072;

  half8 qf[4][2];
#pragma unroll
  for (int qn = 0; qn < 4; ++qn)
#pragma unroll
    for (int ks = 0; ks < 2; ++ks)
      qf[qn][ks] = *(const half8*)(qp + (qn * 2 + ks) * 512 + lane * 8);

  floatx4 oacc[4][4];
#pragma unroll
  for (int qn = 0; qn < 4; ++qn)
#pragma unroll
    for (int i = 0; i < 4; ++i) oacc[qn][i] = (floatx4){0.f, 0.f, 0.f, 0.f};
  float lsum[4] = {0.f, 0.f, 0.f, 0.f};

  const fp16v2 one2 = {(__fp16)1.0f, (__fp16)1.0f};

#pragma unroll 2
  for (int kt = 0; kt < 32; ++kt) {
    const ush* ktp = kp + kt * 4096;
    const ush* vtp = vp + kt * 4096;

    half8 kf[8], vf[8];
#pragma unroll
    for (int i = 0; i < 8; ++i) kf[i] = *(const half8*)(ktp + i * 512 + lane * 8);
#pragma unroll
    for (int i = 0; i < 8; ++i) vf[i] = *(const half8*)(vtp + i * 512 + lane * 8);

#pragma unroll
    for (int qn = 0; qn < 4; ++qn) {
      // ---- scores S^T[key][q] for this 16-q group
      floatx4 s4[4];
#pragma unroll
      for (int jt = 0; jt < 4; ++jt) s4[jt] = (floatx4){0.f, 0.f, 0.f, 0.f};
      __builtin_amdgcn_s_setprio(1);
#pragma unroll
      for (int ks = 0; ks < 2; ++ks)
#pragma unroll
        for (int jt = 0; jt < 4; ++jt)
          s4[jt] = __builtin_amdgcn_mfma_f32_16x16x32_f16(kf[jt * 2 + ks], qf[qn][ks], s4[jt], 0, 0, 0);
      __builtin_amdgcn_s_setprio(0);

      // ---- p = 2^s (raw v_exp_f32); pack into half4 frags
      half4 P[4];
#pragma unroll
      for (int jt = 0; jt < 4; ++jt) {
        float p0 = __builtin_amdgcn_exp2f(s4[jt][0]);
        float p1 = __builtin_amdgcn_exp2f(s4[jt][1]);
        float p2 = __builtin_amdgcn_exp2f(s4[jt][2]);
        float p3 = __builtin_amdgcn_exp2f(s4[jt][3]);
        PK a, b;
        a.v = __builtin_amdgcn_cvt_pkrtz(p0, p1);
        b.v = __builtin_amdgcn_cvt_pkrtz(p2, p3);
        lsum[qn] = __builtin_amdgcn_fdot2(a.v, one2, lsum[qn], false);
        lsum[qn] = __builtin_amdgcn_fdot2(b.v, one2, lsum[qn], false);
        PH ph; ph.u[0] = a.u; ph.u[1] = b.u;
        P[jt] = ph.h;
      }

      // ---- PV via K=32 MFMA: oacc[qn][dt] += P8[s2] x V[s2][dt]
      __builtin_amdgcn_s_setprio(1);
#pragma unroll
      for (int s2 = 0; s2 < 2; ++s2) {
        half8 p8 = __builtin_shufflevector(P[s2 * 2], P[s2 * 2 + 1], 0, 1, 2, 3, 4, 5, 6, 7);
#pragma unroll
        for (int dt = 0; dt < 4; ++dt)
          oacc[qn][dt] = __builtin_amdgcn_mfma_f32_16x16x32_f16(p8, vf[dt * 2 + s2], oacc[qn][dt], 0, 0, 0);
      }
      __builtin_amdgcn_s_setprio(0);
    }
  }

  // ---- denominators: reduce over key-quads, broadcast via wave-private LDS
#pragma unroll
  for (int qn = 0; qn < 4; ++qn) {
    lsum[qn] += __shfl_xor(lsum[qn], 16);
    lsum[qn] += __shfl_xor(lsum[qn], 32);
    Lden[wave][qn * 16 + fr] = lsum[qn];
  }

  // ---- epilogue: wave-private LDS transpose -> coalesced 16B stores.
  // ctx fp16 k-block-major [(kdim/8)][MROWS][8]
  const int b = bh >> 4, h = bh & 15;
#pragma unroll
  for (int qn = 0; qn < 4; ++qn)
#pragma unroll
    for (int r = 0; r < 4; ++r) {
      const float inv = 1.0f / Lden[wave][qn * 16 + fg * 4 + r];
#pragma unroll
      for (int dt = 0; dt < 4; ++dt)
        Tep[wave][qn * 16 + fg * 4 + r][dt * 16 + fr] = f2h(oacc[qn][dt][r] * inv);
    }
  // no barrier needed: Tep is wave-private, DS ops are in-order per wave
  const size_t mrow0 = (size_t)b * SEQ + q0;
  const int kb = lane >> 3;
#pragma unroll
  for (int i = 0; i < 8; ++i) {
    const int q = (lane & 7) + i * 8;
    short8 v = *(const short8*)&Tep[wave][q][kb * 8];
    *(short8*)(ctxf + ((size_t)(h * 8 + kb) * MROWS + mrow0 + q) * 8) = v;
  }
}

// ---------------------------------------------------------------------------
extern "C" void kernel_launch(void* const* d_in, const int* in_sizes, int n_in,
                              void* d_out, int out_size, void* d_ws, size_t ws_size,
                              hipStream_t stream) {
  const float* hs = (const float*)d_in[0];
  const float* Wq = (const float*)d_in[1];
  const float* bq = (const float*)d_in[2];
  const float* Wk = (const float*)d_in[3];
  const float* bk = (const float*)d_in[4];
  const float* Wv = (const float*)d_in[5];
  const float* bv = (const float*)d_in[6];
  const float* Wo = (const float*)d_in[7];
  const float* bo = (const float*)d_in[8];

  ush* qsw  = (ush*)d_ws;                  // 16 MB  frag-swizzled Q (fp16)
  ush* ksw  = qsw + QKV_U16;               // 16 MB  frag-swizzled K
  ush* vsw  = ksw + QKV_U16;               // 16 MB  frag-swizzled V^T (K-frag order)
  ush* hsf  = vsw + QKV_U16;               // 16 MB  hs fp16 k-block-major
  ush* ctxf = hsf + QKV_U16;               // 16 MB  ctx fp16 k-block-major
  ush* Wf4  = ctxf + QKV_U16;              // 8 MB   W fp16 (q,k,v,o)
  float2* sctab = (float2*)(Wf4 + 4 * DMODEL * DMODEL);  // 512 KB sin/cos

  const size_t WS = (size_t)DMODEL * DMODEL;

  cvt_w4<<<dim3(32, 16, 4), 256, 0, stream>>>(Wq, Wk, Wv, Wo, Wf4, sctab);
  cvt_kb<<<dim3(32, 128), 256, 0, stream>>>(hs, hsf, MROWS);

  // Fused Q+K+V projection: 8-wave phase-split, BM=256 -> grid (24,32)
  gemm_f16<1><<<dim3(24, 32), 512, 0, stream>>>(hsf, Wf4, bq, bk, bv,
                                                qsw, ksw, vsw, sctab);

  flash_mfma<<<dim3(8, BH), 256, 0, stream>>>(qsw, ksw, vsw, ctxf);

  // Out-projection: BM=256 -> grid (8,32) = 256 blocks = 1/CU exactly
  gemm_f16<0><<<dim3(8, 32), 512, 0, stream>>>(ctxf, Wf4 + 3 * WS, bo, nullptr, nullptr,
                                               d_out, nullptr, nullptr, sctab);
}